// Round 16
// baseline (267.048 us; speedup 1.0000x reference)
//
#include <hip/hip_runtime.h>
#include <math.h>

#define N_ROWS   65536
#define DIM      256
#define KCODES   1024
#define Q_SIZE   (N_ROWS * DIM)          // 16777216
#define OUT_LOSS Q_SIZE
#define OUT_PERP (Q_SIZE + 1)
#define OUT_IDX  (Q_SIZE + 2)

// flag threshold in scaled-score units (s' = 2^20 * d2-units). Same as r8 (passed).
#define TAUP 200.0f

// ws layout (bytes)
#define WS_LOSS   0        // double
#define WS_RCNT   8        // int
#define WS_E2     16       // float[1024]  original units
#define WS_E2P    4112     // float[1024]  scaled by 2^20
#define WS_COUNTS 8208     // int[1024]
#define WS_IDX    12304    // int[65536]
#define WS_RLIST  274448   // int[65536]
#define WS_ET     536592   // float[262144]   E^T fp32 (refine)
#define WS_P      1585168  // _Float16[262144] packed f16(1024*E) per-wave linear

typedef _Float16 half8 __attribute__((ext_vector_type(8)));
typedef _Float16 half4 __attribute__((ext_vector_type(4)));
typedef float    f32x4 __attribute__((ext_vector_type(4)));

#define ROWB 528    // LDS bytes per X row: 512 (xh) + 16 pad
#define RPB  128    // rows per block (r16: 8-wave block, 2 halves x 4 quarters)

// k_main LDS carve: X 67584 | e2p 4096 = 71680 B
#define LDS_X  0
#define LDS_E2 67584

// ---------------------------------------------------------------------------
// prep: e2, e2p, Et (fp32 transpose, refine), packed P; zero accums.
// P layout: P[q][cb][kk][nt][lane][8 halfs] — per-quarter linear B-frag stream.
// grid 1024 x 256
__global__ void k_prep(const float* __restrict__ E, float* __restrict__ e2,
                       float* __restrict__ e2p, float* __restrict__ Et,
                       _Float16* __restrict__ P,
                       int* __restrict__ counts, double* __restrict__ loss,
                       int* __restrict__ rcnt) {
    int b = blockIdx.x, t = threadIdx.x;
    __shared__ double red[256];
    float v = E[b * DIM + t];
    red[t] = (double)v * (double)v;

    {   // packed B-stream write
        int o   = b * 256 + t;
        int j    = o & 7;
        int lane = (o >> 3) & 63;
        int nt   = (o >> 9) & 3;
        int kk   = (o >> 11) & 7;
        int cbq  = o >> 14;            // 0..15
        int q = cbq >> 2, cb = cbq & 3;
        int code = q * 256 + cb * 64 + nt * 16 + (lane & 15);
        int d    = (lane >> 4) * 8 + kk * 32 + j;
        P[o] = (_Float16)(E[code * DIM + d] * 1024.0f);   // exact scaling, RN
    }

    __syncthreads();
    for (int s = 128; s > 0; s >>= 1) {
        if (t < s) red[t] += red[t + s];
        __syncthreads();
    }
    if (t == 0) { e2[b] = (float)red[0]; e2p[b] = (float)(red[0] * 1048576.0); }

    int o = b * 256 + t;
    int d = o >> 10, k = o & 1023;
    Et[o] = E[k * DIM + d];

    if (b < 4) counts[b * 256 + t] = 0;
    if (b == 0 && t == 0) { *loss = 0.0; *rcnt = 0; }
}

// ---------------------------------------------------------------------------
// main: MFMA ranking, single f16 product xh*Eh (per-(row,code) accumulation
// bit-identical to r8-r15 — only the wave->work mapping changed).
// r16: 512-thread block (8 waves = 2/SIMD guaranteed co-residency), RPB=128.
// Wave w: half h=w>>2 (rows h*64..h*64+63), quarter q=w&3 (codes q*256..).
// Rationale: r8-r15 established k_main is per-CU B-fill-bandwidth-bound
// (~24 GB/s/CU, the m13 per-CU ceiling); every schedule variant was null.
// This halves B bytes per row (512KB covers 128 rows), and the two waves
// sharing a quarter-stream should L1-hit the duplicate reads.
// V0-style mod-3 depth-2 prefetch, counted vmcnt(8), issue-before-wait.
// grid 512 x 512
__global__ void __launch_bounds__(512)
k_main(const float* __restrict__ X, const _Float16* __restrict__ P,
       const float* __restrict__ e2p,
       int* __restrict__ idx_ws, int* __restrict__ rlist,
       int* __restrict__ rcnt) {
    __shared__ __align__(16) char sAll[71680];
    const int tid  = threadIdx.x;
    const int wid  = tid >> 6;
    const int lane = tid & 63;
    const int c16  = lane & 15;
    const int kg   = lane >> 4;
    const int q    = wid & 3;           // code quarter
    const int h    = wid >> 2;          // row half
    const int rb   = blockIdx.x * RPB;

    char* sA = sAll + LDS_X;

    // ---- stage X -> f16 in LDS (128 rows); stage e2p -> LDS ----
    {
        const float4* Xg = (const float4*)(X + (size_t)rb * DIM);
        #pragma unroll
        for (int it = 0; it < 16; ++it) {
            int f = it * 512 + tid;           // 0..8191 float4 slots
            int row = f >> 6, d4 = f & 63;
            float4 v = Xg[(size_t)row * 64 + d4];
            half4 hh = {(_Float16)v.x, (_Float16)v.y, (_Float16)v.z, (_Float16)v.w};
            *(half4*)(sA + row * ROWB + d4 * 8) = hh;
        }
        if (tid < 256)
            ((float4*)(sAll + LDS_E2))[tid] = ((const float4*)e2p)[tid];
    }
    __syncthreads();   // drains staging vmem — in-loop vmcnt counts only B loads

    // per-quarter contiguous B stream: 128 KB, lane offset 16B
    const char* gB = (const char*)P + (size_t)q * 131072 + (size_t)lane * 16;
#define GLOADC(dst, c)                                                        \
    asm volatile("global_load_dwordx4 %0, %1, off"                            \
                 : "=v"(dst)                                                  \
                 : "v"(gB + (size_t)((c) * 1024))                             \
                 : "memory")
#define VMW(n) { asm volatile("s_waitcnt vmcnt(" #n ")" ::: "memory");        \
                 __builtin_amdgcn_sched_barrier(0); }

    int Abase[4];
    #pragma unroll
    for (int mt = 0; mt < 4; ++mt)
        Abase[mt] = (h * 64 + mt * 16 + c16) * ROWB + kg * 16;

    float tb1[16], tb2[16];
    int   ti1[16];
    #pragma unroll
    for (int i = 0; i < 16; ++i) { tb1[i] = 3.4e38f; tb2[i] = 3.4e38f; ti1[i] = 0; }

    const int cw = q * 256;
    const float* sE2 = (const float*)(sAll + LDS_E2);

    f32x4 acc[4][4];

    // mod-3 depth-2 pipeline (r14 V0 structure)
    half8 b[3][4];
    #pragma unroll
    for (int nt = 0; nt < 4; ++nt) GLOADC(b[0][nt], 0 * 4 + nt);
    #pragma unroll
    for (int nt = 0; nt < 4; ++nt) GLOADC(b[1][nt], 1 * 4 + nt);

    #pragma unroll
    for (int s = 0; s < 32; ++s) {
        const int kk = s & 7;
        if (kk == 0) {
            #pragma unroll
            for (int mt = 0; mt < 4; ++mt)
                #pragma unroll
                for (int nt = 0; nt < 4; ++nt) acc[mt][nt] = 0.0f;
        }
        if (s <= 29) {
            #pragma unroll
            for (int nt = 0; nt < 4; ++nt) GLOADC(b[(s + 2) % 3][nt], (s + 2) * 4 + nt);
        }
        if (s <= 29)      VMW(8)
        else if (s == 30) VMW(4)
        else              VMW(0)

        half8 ah[4];
        #pragma unroll
        for (int mt = 0; mt < 4; ++mt)
            ah[mt] = *(const half8*)(sA + Abase[mt] + kk * 64);

        #pragma unroll
        for (int mt = 0; mt < 4; ++mt) {
            acc[mt][0] = __builtin_amdgcn_mfma_f32_16x16x32_f16(ah[mt], b[s % 3][0], acc[mt][0], 0, 0, 0);
            acc[mt][1] = __builtin_amdgcn_mfma_f32_16x16x32_f16(ah[mt], b[s % 3][1], acc[mt][1], 0, 0, 0);
            acc[mt][2] = __builtin_amdgcn_mfma_f32_16x16x32_f16(ah[mt], b[s % 3][2], acc[mt][2], 0, 0, 0);
            acc[mt][3] = __builtin_amdgcn_mfma_f32_16x16x32_f16(ah[mt], b[s % 3][3], acc[mt][3], 0, 0, 0);
        }

        if (kk == 7) {
            // epilogue: s' = e2' - 2048*dot', sorted-insert top-2 (med3 form)
            const int cb = s >> 3;
            const int cbase = cw + cb * 64;
            const int c0 = cbase + c16;
            float e2v[4];
            #pragma unroll
            for (int nt = 0; nt < 4; ++nt) e2v[nt] = sE2[c0 + nt * 16];
            #pragma unroll
            for (int mt = 0; mt < 4; ++mt)
                #pragma unroll
                for (int nt = 0; nt < 4; ++nt) {
                    int code = cbase + nt * 16 + c16;
                    #pragma unroll
                    for (int r = 0; r < 4; ++r) {
                        float sc = fmaf(-2048.0f, acc[mt][nt][r], e2v[nt]);
                        int ix = mt * 4 + r;
                        tb2[ix] = __builtin_amdgcn_fmed3f(tb1[ix], tb2[ix], sc);
                        bool lt = sc < tb1[ix];
                        tb1[ix] = lt ? sc : tb1[ix];
                        ti1[ix] = lt ? code : ti1[ix];
                    }
                }
        }
    }
#undef GLOADC
#undef VMW

    // ---- butterfly merge across the 16 col-lanes of each kg group ----
    #pragma unroll
    for (int ix = 0; ix < 16; ++ix) {
        float v1 = tb1[ix], v2 = tb2[ix];
        int   j1 = ti1[ix];
        #pragma unroll
        for (int m = 1; m < 16; m <<= 1) {
            float ov1 = __shfl_xor(v1, m, 64);
            int   oj1 = __shfl_xor(j1, m, 64);
            float ov2 = __shfl_xor(v2, m, 64);
            bool take = (ov1 < v1) || (ov1 == v1 && oj1 < j1);
            float losr = take ? v1 : ov1;
            v1 = take ? ov1 : v1;
            j1 = take ? oj1 : j1;
            v2 = fminf(fminf(v2, ov2), losr);
        }
        tb1[ix] = v1; tb2[ix] = v2; ti1[ix] = j1;
    }

    // ---- cross-wave merge via LDS (reuse sA region): [128 rows][4 quarters] ----
    __syncthreads();
    float* mB1 = (float*)sA;            // [128][4]
    float* mB2 = (float*)(sA + 2048);   // [128][4]
    int*   mI1 = (int*)(sA + 4096);     // [128][4]
    #pragma unroll
    for (int ix = 0; ix < 16; ++ix) {
        if (c16 == ix) {
            int row = h * 64 + (ix >> 2) * 16 + kg * 4 + (ix & 3);
            mB1[row * 4 + q] = tb1[ix];
            mB2[row * 4 + q] = tb2[ix];
            mI1[row * 4 + q] = ti1[ix];
        }
    }
    __syncthreads();
    if (tid < RPB) {
        float m1 = 3.4e38f, m2 = 3.4e38f;
        int mi = 0;
        #pragma unroll
        for (int w = 0; w < 4; ++w) {
            float v = mB1[tid * 4 + w];
            int  id = mI1[tid * 4 + w];
            float u = mB2[tid * 4 + w];
            bool take = (v < m1) || (v == m1 && id < mi);
            float losr = take ? m1 : v;
            m1 = take ? v : m1;
            mi = take ? id : mi;
            m2 = fminf(fminf(m2, u), losr);
        }
        int g = rb + tid;
        idx_ws[g] = mi;
        if (m2 - m1 < TAUP) {
            int slot = atomicAdd(rcnt, 1);
            rlist[slot] = g;
        }
    }
}

// ---------------------------------------------------------------------------
// refine: exact reference-fp32 replication, 8 rows per Et sweep (r16: halves
// Et traffic vs 4-row; safe now — r9's spill was the DEFAULT 1024-thread
// launch-bounds capping regs at 128/wave; (256,1) caps at 512).
// d-loop unrolled x4; fp64 accumulation order per accumulator UNCHANGED.
// grid 1024 x 256
__launch_bounds__(256, 1)
__global__ void k_refine(const float* __restrict__ X, const float* __restrict__ Et,
                         const float* __restrict__ e2,
                         const int* __restrict__ rlist, const int* __restrict__ rcnt,
                         int* __restrict__ idx_ws) {
    __shared__ float xs[8][256];
    __shared__ float sbv[8][256];
    __shared__ int   sbi[8][256];
    __shared__ float x2s[8];
    __shared__ int   rows[8];
    const int cnt = *rcnt;
    const int t = threadIdx.x;
    for (int base = blockIdx.x * 8; base < cnt; base += gridDim.x * 8) {
        __syncthreads();
        if (t < 8) {
            int e = base + t;
            rows[t] = rlist[e < cnt ? e : (cnt - 1)];
        }
        __syncthreads();
        // stage 8 rows of X (512 float4 slots)
        #pragma unroll
        for (int i = 0; i < 2; ++i) {
            int idx = t + i * 256;
            int r = idx >> 6, c4 = idx & 63;
            ((float4*)xs[r])[c4] = ((const float4*)(X + (size_t)rows[r] * DIM))[c4];
        }
        __syncthreads();
        // x2_32 per row (fp64 serial over d, fl32) — same order as reference path
        if (t < 8) {
            double s = 0.0;
            for (int d = 0; d < DIM; ++d) { double xv = (double)xs[t][d]; s += xv * xv; }
            x2s[t] = (float)s;
        }
        __syncthreads();

        // fp64 dots: thread t owns codes {t, t+256, t+512, t+768} for 8 rows
        double a0[8], a1[8], a2[8], a3[8];
        #pragma unroll
        for (int r = 0; r < 8; ++r) { a0[r] = 0.0; a1[r] = 0.0; a2[r] = 0.0; a3[r] = 0.0; }
        #pragma unroll 4
        for (int d = 0; d < DIM; ++d) {
            double e0 = (double)Et[d * KCODES + t];
            double e1 = (double)Et[d * KCODES + 256 + t];
            double e2d = (double)Et[d * KCODES + 512 + t];
            double e3 = (double)Et[d * KCODES + 768 + t];
            #pragma unroll
            for (int r = 0; r < 8; ++r) {
                double xv = (double)xs[r][d];
                a0[r] += xv * e0;
                a1[r] += xv * e1;
                a2[r] += xv * e2d;
                a3[r] += xv * e3;
            }
        }

        // per-thread best over its 4 codes, per row (fp32-replicated pipeline)
        const float eA = e2[t], eB = e2[256 + t], eC = e2[512 + t], eD = e2[768 + t];
        #pragma unroll
        for (int r = 0; r < 8; ++r) {
            float best = 3.4e38f; int bk = 0;
            float x2 = x2s[r];
            { float d2 = fmaf(-2.f, (float)a0[r], x2 + eA); if (d2 < best) { best = d2; bk = t; } }
            { float d2 = fmaf(-2.f, (float)a1[r], x2 + eB); if (d2 < best) { best = d2; bk = 256 + t; } }
            { float d2 = fmaf(-2.f, (float)a2[r], x2 + eC); if (d2 < best) { best = d2; bk = 512 + t; } }
            { float d2 = fmaf(-2.f, (float)a3[r], x2 + eD); if (d2 < best) { best = d2; bk = 768 + t; } }
            sbv[r][t] = best; sbi[r][t] = bk;
        }
        __syncthreads();
        // final reduce: wave w handles rows 2w, 2w+1
        {
            const int w = t >> 6, lane = t & 63;
            #pragma unroll
            for (int i = 0; i < 2; ++i) {
                int r = w * 2 + i;
                float v = sbv[r][lane];     int id = sbi[r][lane];
                #pragma unroll
                for (int c = 1; c < 4; ++c) {
                    float ov = sbv[r][lane + 64 * c]; int oi = sbi[r][lane + 64 * c];
                    if (ov < v || (ov == v && oi < id)) { v = ov; id = oi; }
                }
                #pragma unroll
                for (int m = 1; m < 64; m <<= 1) {
                    float ov = __shfl_xor(v, m, 64);
                    int   oi = __shfl_xor(id, m, 64);
                    if (ov < v || (ov == v && oi < id)) { v = ov; id = oi; }
                }
                if (lane == 0 && base + r < cnt) idx_ws[rows[r]] = id;
            }
        }
    }
}

// ---------------------------------------------------------------------------
// out: quantized rows, index output, loss, histogram. One fp64 atomic/block.
// grid 1024 x 256
__launch_bounds__(256)
__global__ void k_out(const float* __restrict__ X, const float* __restrict__ E,
                      const int* __restrict__ idx_ws, float* __restrict__ out,
                      int* __restrict__ counts, double* __restrict__ loss) {
    const int tid = threadIdx.x;
    const int w = tid >> 6, lane = tid & 63;
    const int rbase = blockIdx.x * 64;
    double ls = 0.0;
    #pragma unroll 4
    for (int it = 0; it < 16; ++it) {
        const int row = rbase + it * 4 + w;
        const int k = idx_ws[row];
        float4 q = ((const float4*)(E + (size_t)k * DIM))[lane];
        float4 x = ((const float4*)(X + (size_t)row * DIM))[lane];
        ((float4*)(out + (size_t)row * DIM))[lane] = q;
        double d0 = (double)q.x - (double)x.x;
        double d1 = (double)q.y - (double)x.y;
        double d2 = (double)q.z - (double)x.z;
        double d3 = (double)q.w - (double)x.w;
        ls += d0 * d0 + d1 * d1 + d2 * d2 + d3 * d3;
        if (lane == 0) {
            atomicAdd(&counts[k], 1);
            out[OUT_IDX + row] = (float)k;
        }
    }
    __shared__ double red[256];
    red[tid] = ls;
    __syncthreads();
    for (int s = 128; s > 0; s >>= 1) {
        if (tid < s) red[tid] += red[tid + s];
        __syncthreads();
    }
    if (tid == 0) atomicAdd(loss, red[0]);
}

// ---------------------------------------------------------------------------
// fin: scalars
__global__ void k_fin(const int* __restrict__ counts, const double* __restrict__ loss,
                      float* __restrict__ out) {
    int t = threadIdx.x;
    __shared__ double red[256];
    double h = 0.0;
    #pragma unroll
    for (int i = 0; i < 4; ++i) {
        double p = (double)counts[t + i * 256] / (double)N_ROWS;
        h += p * log(p + 1e-10);
    }
    red[t] = h;
    __syncthreads();
    for (int s = 128; s > 0; s >>= 1) {
        if (t < s) red[t] += red[t + s];
        __syncthreads();
    }
    if (t == 0) {
        out[OUT_PERP] = (float)exp(-red[0]);
        out[OUT_LOSS] = (float)((*loss) / (double)Q_SIZE * 1.25);
    }
}

// ---------------------------------------------------------------------------
extern "C" void kernel_launch(void* const* d_in, const int* in_sizes, int n_in,
                              void* d_out, int out_size, void* d_ws, size_t ws_size,
                              hipStream_t stream) {
    (void)in_sizes; (void)n_in; (void)out_size; (void)ws_size;
    const float* X = (const float*)d_in[0];
    const float* E = (const float*)d_in[1];
    float* out = (float*)d_out;
    char* ws = (char*)d_ws;

    double*    loss   = (double*)(ws + WS_LOSS);
    int*       rcnt   = (int*)(ws + WS_RCNT);
    float*     e2     = (float*)(ws + WS_E2);
    float*     e2p    = (float*)(ws + WS_E2P);
    int*       counts = (int*)(ws + WS_COUNTS);
    int*       idx_ws = (int*)(ws + WS_IDX);
    int*       rlist  = (int*)(ws + WS_RLIST);
    float*     Et     = (float*)(ws + WS_ET);
    _Float16*  Pp     = (_Float16*)(ws + WS_P);

    k_prep<<<1024, 256, 0, stream>>>(E, e2, e2p, Et, Pp, counts, loss, rcnt);
    k_main<<<N_ROWS / RPB, 512, 0, stream>>>(X, Pp, e2p, idx_ws, rlist, rcnt);
    k_refine<<<1024, 256, 0, stream>>>(X, Et, e2, rlist, rcnt, idx_ws);
    k_out<<<1024, 256, 0, stream>>>(X, E, idx_ws, out, counts, loss);
    k_fin<<<1, 256, 0, stream>>>(counts, loss, out);
}

// Round 17
// 207.367 us; speedup vs baseline: 1.2878x; 1.2878x over previous
//
#include <hip/hip_runtime.h>
#include <math.h>

#define N_ROWS   65536
#define DIM      256
#define KCODES   1024
#define Q_SIZE   (N_ROWS * DIM)          // 16777216
#define OUT_LOSS Q_SIZE
#define OUT_PERP (Q_SIZE + 1)
#define OUT_IDX  (Q_SIZE + 2)

// flag threshold in scaled-score units (s' = 2^20 * d2-units). Same as r8 (passed).
#define TAUP 200.0f

// ws layout (bytes)
#define WS_LOSS   0        // double
#define WS_RCNT   8        // int
#define WS_E2     16       // float[1024]  original units
#define WS_E2P    4112     // float[1024]  scaled by 2^20
#define WS_COUNTS 8208     // int[1024]
#define WS_IDX    12304    // int[65536]
#define WS_RLIST  274448   // int[65536]
#define WS_ET     536592   // float[262144]   E^T fp32 (refine)
#define WS_P      1585168  // _Float16[262144] packed f16(1024*E) per-wave linear

typedef _Float16 half8 __attribute__((ext_vector_type(8)));
typedef _Float16 half4 __attribute__((ext_vector_type(4)));
typedef float    f32x4 __attribute__((ext_vector_type(4)));

#define ROWB 528    // LDS bytes per X row: 512 (xh) + 16 pad
#define RPB  64     // rows per block (r12-proven geometry)

// k_main LDS carve: X 33792 | e2p 4096 = 37888 B (B in registers)
#define LDS_X  0
#define LDS_E2 33792

// ---------------------------------------------------------------------------
// prep: e2, e2p, Et (fp32 transpose, refine), packed P; zero accums.
// P layout: P[q][cb][kk][nt][lane][8 halfs] — per-quarter linear B-frag stream.
// grid 1024 x 256
__global__ void k_prep(const float* __restrict__ E, float* __restrict__ e2,
                       float* __restrict__ e2p, float* __restrict__ Et,
                       _Float16* __restrict__ P,
                       int* __restrict__ counts, double* __restrict__ loss,
                       int* __restrict__ rcnt) {
    int b = blockIdx.x, t = threadIdx.x;
    __shared__ double red[256];
    float v = E[b * DIM + t];
    red[t] = (double)v * (double)v;

    {   // packed B-stream write
        int o   = b * 256 + t;
        int j    = o & 7;
        int lane = (o >> 3) & 63;
        int nt   = (o >> 9) & 3;
        int kk   = (o >> 11) & 7;
        int cbq  = o >> 14;            // 0..15
        int q = cbq >> 2, cb = cbq & 3;
        int code = q * 256 + cb * 64 + nt * 16 + (lane & 15);
        int d    = (lane >> 4) * 8 + kk * 32 + j;
        P[o] = (_Float16)(E[code * DIM + d] * 1024.0f);   // exact scaling, RN
    }

    __syncthreads();
    for (int s = 128; s > 0; s >>= 1) {
        if (t < s) red[t] += red[t + s];
        __syncthreads();
    }
    if (t == 0) { e2[b] = (float)red[0]; e2p[b] = (float)(red[0] * 1048576.0); }

    int o = b * 256 + t;
    int d = o >> 10, k = o & 1023;
    Et[o] = E[k * DIM + d];

    if (b < 4) counts[b * 256 + t] = 0;
    if (b == 0 && t == 0) { *loss = 0.0; *rcnt = 0; }
}

// ---------------------------------------------------------------------------
// main (r17 A/B): NT=0 is the r12-exact control; NT=1 stages X with
// NON-TEMPORAL loads. Theory: r12's aggregate B rate (512MB/87µs = 5.9 TB/s)
// sits at the L3-class ceiling, 6x under L2 — X staging bursts (132KB/block
// x 1024 blocks) evict the 512KB P set from L2, forcing L3 re-fetches.
// NT staging should leave P L2-resident. Numerics bit-identical in both.
// V0-style mod-3 depth-2 register pipeline, counted vmcnt(8) (r12/r14).
// OCCUPANCY NOTE (r4-r7,r16): never cap waves — it spills. 256 thr, no bound.
// grid 512 x 256 each (rows split A/B)
template <int NT>
__global__ void __launch_bounds__(256)
k_mainT(const float* __restrict__ X, const _Float16* __restrict__ P,
        const float* __restrict__ e2p,
        int* __restrict__ idx_ws, int* __restrict__ rlist,
        int* __restrict__ rcnt, int row_off) {
    __shared__ __align__(16) char sAll[37888];
    const int tid  = threadIdx.x;
    const int wid  = tid >> 6;
    const int lane = tid & 63;
    const int c16  = lane & 15;
    const int kg   = lane >> 4;
    const int rb   = row_off + blockIdx.x * RPB;

    char* sA = sAll + LDS_X;

    // ---- stage X -> f16 in LDS; stage e2p -> LDS ----
    {
        const f32x4* Xg = (const f32x4*)(X + (size_t)rb * DIM);
        #pragma unroll
        for (int it = 0; it < 16; ++it) {
            int f = it * 256 + tid;
            int row = f >> 6, d4 = f & 63;
            f32x4 v;
            if constexpr (NT) v = __builtin_nontemporal_load(&Xg[(size_t)row * 64 + d4]);
            else              v = Xg[(size_t)row * 64 + d4];
            half4 hh = {(_Float16)v[0], (_Float16)v[1], (_Float16)v[2], (_Float16)v[3]};
            *(half4*)(sA + row * ROWB + d4 * 8) = hh;
        }
        ((f32x4*)(sAll + LDS_E2))[tid] = ((const f32x4*)e2p)[tid];
    }
    __syncthreads();   // drains staging vmem — in-loop vmcnt counts only B loads

    // per-wave contiguous B stream: 128 KB per quarter, lane offset 16B
    const char* gB = (const char*)P + (size_t)wid * 131072 + (size_t)lane * 16;
#define GLOADC(dst, c)                                                        \
    asm volatile("global_load_dwordx4 %0, %1, off"                            \
                 : "=v"(dst)                                                  \
                 : "v"(gB + (size_t)((c) * 1024))                             \
                 : "memory")
#define VMW(n) { asm volatile("s_waitcnt vmcnt(" #n ")" ::: "memory");        \
                 __builtin_amdgcn_sched_barrier(0); }

    int Abase[4];
    #pragma unroll
    for (int mt = 0; mt < 4; ++mt) Abase[mt] = (mt * 16 + c16) * ROWB + kg * 16;

    float tb1[16], tb2[16];
    int   ti1[16];
    #pragma unroll
    for (int i = 0; i < 16; ++i) { tb1[i] = 3.4e38f; tb2[i] = 3.4e38f; ti1[i] = 0; }

    const int cw = wid * 256;
    const float* sE2 = (const float*)(sAll + LDS_E2);

    f32x4 acc[4][4];

    // mod-3 depth-2 register pipeline (r14 V0 structure)
    half8 b[3][4];
    #pragma unroll
    for (int nt = 0; nt < 4; ++nt) GLOADC(b[0][nt], 0 * 4 + nt);
    #pragma unroll
    for (int nt = 0; nt < 4; ++nt) GLOADC(b[1][nt], 1 * 4 + nt);

    #pragma unroll
    for (int s = 0; s < 32; ++s) {
        const int kk = s & 7;
        if (kk == 0) {
            #pragma unroll
            for (int mt = 0; mt < 4; ++mt)
                #pragma unroll
                for (int nt = 0; nt < 4; ++nt) acc[mt][nt] = 0.0f;
        }
        if (s <= 29) {
            #pragma unroll
            for (int nt = 0; nt < 4; ++nt) GLOADC(b[(s + 2) % 3][nt], (s + 2) * 4 + nt);
        }
        if (s <= 29)      VMW(8)
        else if (s == 30) VMW(4)
        else              VMW(0)

        half8 ah[4];
        #pragma unroll
        for (int mt = 0; mt < 4; ++mt)
            ah[mt] = *(const half8*)(sA + Abase[mt] + kk * 64);

        #pragma unroll
        for (int mt = 0; mt < 4; ++mt) {
            acc[mt][0] = __builtin_amdgcn_mfma_f32_16x16x32_f16(ah[mt], b[s % 3][0], acc[mt][0], 0, 0, 0);
            acc[mt][1] = __builtin_amdgcn_mfma_f32_16x16x32_f16(ah[mt], b[s % 3][1], acc[mt][1], 0, 0, 0);
            acc[mt][2] = __builtin_amdgcn_mfma_f32_16x16x32_f16(ah[mt], b[s % 3][2], acc[mt][2], 0, 0, 0);
            acc[mt][3] = __builtin_amdgcn_mfma_f32_16x16x32_f16(ah[mt], b[s % 3][3], acc[mt][3], 0, 0, 0);
        }

        if (kk == 7) {
            // epilogue: s' = e2' - 2048*dot', sorted-insert top-2 (med3 form)
            const int cb = s >> 3;
            const int cbase = cw + cb * 64;
            const int c0 = cbase + c16;
            float e2v[4];
            #pragma unroll
            for (int nt = 0; nt < 4; ++nt) e2v[nt] = sE2[c0 + nt * 16];
            #pragma unroll
            for (int mt = 0; mt < 4; ++mt)
                #pragma unroll
                for (int nt = 0; nt < 4; ++nt) {
                    int code = cbase + nt * 16 + c16;
                    #pragma unroll
                    for (int r = 0; r < 4; ++r) {
                        float sc = fmaf(-2048.0f, acc[mt][nt][r], e2v[nt]);
                        int ix = mt * 4 + r;
                        tb2[ix] = __builtin_amdgcn_fmed3f(tb1[ix], tb2[ix], sc);
                        bool lt = sc < tb1[ix];
                        tb1[ix] = lt ? sc : tb1[ix];
                        ti1[ix] = lt ? code : ti1[ix];
                    }
                }
        }
    }
#undef GLOADC
#undef VMW

    // ---- butterfly merge across the 16 col-lanes of each kg group ----
    #pragma unroll
    for (int ix = 0; ix < 16; ++ix) {
        float v1 = tb1[ix], v2 = tb2[ix];
        int   j1 = ti1[ix];
        #pragma unroll
        for (int m = 1; m < 16; m <<= 1) {
            float ov1 = __shfl_xor(v1, m, 64);
            int   oj1 = __shfl_xor(j1, m, 64);
            float ov2 = __shfl_xor(v2, m, 64);
            bool take = (ov1 < v1) || (ov1 == v1 && oj1 < j1);
            float losr = take ? v1 : ov1;
            v1 = take ? ov1 : v1;
            j1 = take ? oj1 : j1;
            v2 = fminf(fminf(v2, ov2), losr);
        }
        tb1[ix] = v1; tb2[ix] = v2; ti1[ix] = j1;
    }

    // ---- cross-wave merge via LDS (reuse sA region) ----
    __syncthreads();
    float* mB1 = (float*)sA;            // [64][4]
    float* mB2 = (float*)(sA + 1024);   // [64][4]
    int*   mI1 = (int*)(sA + 2048);     // [64][4]
    #pragma unroll
    for (int ix = 0; ix < 16; ++ix) {
        if (c16 == ix) {
            int row = (ix >> 2) * 16 + kg * 4 + (ix & 3);
            mB1[row * 4 + wid] = tb1[ix];
            mB2[row * 4 + wid] = tb2[ix];
            mI1[row * 4 + wid] = ti1[ix];
        }
    }
    __syncthreads();
    if (tid < RPB) {
        float m1 = 3.4e38f, m2 = 3.4e38f;
        int mi = 0;
        #pragma unroll
        for (int w = 0; w < 4; ++w) {
            float v = mB1[tid * 4 + w];
            int  id = mI1[tid * 4 + w];
            float u = mB2[tid * 4 + w];
            bool take = (v < m1) || (v == m1 && id < mi);
            float losr = take ? m1 : v;
            m1 = take ? v : m1;
            mi = take ? id : mi;
            m2 = fminf(fminf(m2, u), losr);
        }
        int g = rb + tid;
        idx_ws[g] = mi;
        if (m2 - m1 < TAUP) {
            int slot = atomicAdd(rcnt, 1);
            rlist[slot] = g;
        }
    }
}

// ---------------------------------------------------------------------------
// refine: exact reference-fp32 replication, 8 rows per Et sweep (r16 version,
// correctness-proven). r9's spill was the DEFAULT 1024-thread bound capping
// regs at 128/wave; (256,1) caps at 512 so 64 fp64 acc regs fit.
// d-loop unrolled x4; fp64 accumulation order per accumulator UNCHANGED.
// grid 1024 x 256
__launch_bounds__(256, 1)
__global__ void k_refine(const float* __restrict__ X, const float* __restrict__ Et,
                         const float* __restrict__ e2,
                         const int* __restrict__ rlist, const int* __restrict__ rcnt,
                         int* __restrict__ idx_ws) {
    __shared__ float xs[8][256];
    __shared__ float sbv[8][256];
    __shared__ int   sbi[8][256];
    __shared__ float x2s[8];
    __shared__ int   rows[8];
    const int cnt = *rcnt;
    const int t = threadIdx.x;
    for (int base = blockIdx.x * 8; base < cnt; base += gridDim.x * 8) {
        __syncthreads();
        if (t < 8) {
            int e = base + t;
            rows[t] = rlist[e < cnt ? e : (cnt - 1)];
        }
        __syncthreads();
        #pragma unroll
        for (int i = 0; i < 2; ++i) {
            int idx = t + i * 256;
            int r = idx >> 6, c4 = idx & 63;
            ((float4*)xs[r])[c4] = ((const float4*)(X + (size_t)rows[r] * DIM))[c4];
        }
        __syncthreads();
        if (t < 8) {
            double s = 0.0;
            for (int d = 0; d < DIM; ++d) { double xv = (double)xs[t][d]; s += xv * xv; }
            x2s[t] = (float)s;
        }
        __syncthreads();

        double a0[8], a1[8], a2[8], a3[8];
        #pragma unroll
        for (int r = 0; r < 8; ++r) { a0[r] = 0.0; a1[r] = 0.0; a2[r] = 0.0; a3[r] = 0.0; }
        #pragma unroll 4
        for (int d = 0; d < DIM; ++d) {
            double e0 = (double)Et[d * KCODES + t];
            double e1 = (double)Et[d * KCODES + 256 + t];
            double e2d = (double)Et[d * KCODES + 512 + t];
            double e3 = (double)Et[d * KCODES + 768 + t];
            #pragma unroll
            for (int r = 0; r < 8; ++r) {
                double xv = (double)xs[r][d];
                a0[r] += xv * e0;
                a1[r] += xv * e1;
                a2[r] += xv * e2d;
                a3[r] += xv * e3;
            }
        }

        const float eA = e2[t], eB = e2[256 + t], eC = e2[512 + t], eD = e2[768 + t];
        #pragma unroll
        for (int r = 0; r < 8; ++r) {
            float best = 3.4e38f; int bk = 0;
            float x2 = x2s[r];
            { float d2 = fmaf(-2.f, (float)a0[r], x2 + eA); if (d2 < best) { best = d2; bk = t; } }
            { float d2 = fmaf(-2.f, (float)a1[r], x2 + eB); if (d2 < best) { best = d2; bk = 256 + t; } }
            { float d2 = fmaf(-2.f, (float)a2[r], x2 + eC); if (d2 < best) { best = d2; bk = 512 + t; } }
            { float d2 = fmaf(-2.f, (float)a3[r], x2 + eD); if (d2 < best) { best = d2; bk = 768 + t; } }
            sbv[r][t] = best; sbi[r][t] = bk;
        }
        __syncthreads();
        {
            const int w = t >> 6, lane = t & 63;
            #pragma unroll
            for (int i = 0; i < 2; ++i) {
                int r = w * 2 + i;
                float v = sbv[r][lane];     int id = sbi[r][lane];
                #pragma unroll
                for (int c = 1; c < 4; ++c) {
                    float ov = sbv[r][lane + 64 * c]; int oi = sbi[r][lane + 64 * c];
                    if (ov < v || (ov == v && oi < id)) { v = ov; id = oi; }
                }
                #pragma unroll
                for (int m = 1; m < 64; m <<= 1) {
                    float ov = __shfl_xor(v, m, 64);
                    int   oi = __shfl_xor(id, m, 64);
                    if (ov < v || (ov == v && oi < id)) { v = ov; id = oi; }
                }
                if (lane == 0 && base + r < cnt) idx_ws[rows[r]] = id;
            }
        }
    }
}

// ---------------------------------------------------------------------------
// out: quantized rows, index output, loss, histogram. One fp64 atomic/block.
// grid 1024 x 256
__launch_bounds__(256)
__global__ void k_out(const float* __restrict__ X, const float* __restrict__ E,
                      const int* __restrict__ idx_ws, float* __restrict__ out,
                      int* __restrict__ counts, double* __restrict__ loss) {
    const int tid = threadIdx.x;
    const int w = tid >> 6, lane = tid & 63;
    const int rbase = blockIdx.x * 64;
    double ls = 0.0;
    #pragma unroll 4
    for (int it = 0; it < 16; ++it) {
        const int row = rbase + it * 4 + w;
        const int k = idx_ws[row];
        float4 q = ((const float4*)(E + (size_t)k * DIM))[lane];
        float4 x = ((const float4*)(X + (size_t)row * DIM))[lane];
        ((float4*)(out + (size_t)row * DIM))[lane] = q;
        double d0 = (double)q.x - (double)x.x;
        double d1 = (double)q.y - (double)x.y;
        double d2 = (double)q.z - (double)x.z;
        double d3 = (double)q.w - (double)x.w;
        ls += d0 * d0 + d1 * d1 + d2 * d2 + d3 * d3;
        if (lane == 0) {
            atomicAdd(&counts[k], 1);
            out[OUT_IDX + row] = (float)k;
        }
    }
    __shared__ double red[256];
    red[tid] = ls;
    __syncthreads();
    for (int s = 128; s > 0; s >>= 1) {
        if (tid < s) red[tid] += red[tid + s];
        __syncthreads();
    }
    if (tid == 0) atomicAdd(loss, red[0]);
}

// ---------------------------------------------------------------------------
// fin: scalars
__global__ void k_fin(const int* __restrict__ counts, const double* __restrict__ loss,
                      float* __restrict__ out) {
    int t = threadIdx.x;
    __shared__ double red[256];
    double h = 0.0;
    #pragma unroll
    for (int i = 0; i < 4; ++i) {
        double p = (double)counts[t + i * 256] / (double)N_ROWS;
        h += p * log(p + 1e-10);
    }
    red[t] = h;
    __syncthreads();
    for (int s = 128; s > 0; s >>= 1) {
        if (t < s) red[t] += red[t + s];
        __syncthreads();
    }
    if (t == 0) {
        out[OUT_PERP] = (float)exp(-red[0]);
        out[OUT_LOSS] = (float)((*loss) / (double)Q_SIZE * 1.25);
    }
}

// ---------------------------------------------------------------------------
extern "C" void kernel_launch(void* const* d_in, const int* in_sizes, int n_in,
                              void* d_out, int out_size, void* d_ws, size_t ws_size,
                              hipStream_t stream) {
    (void)in_sizes; (void)n_in; (void)out_size; (void)ws_size;
    const float* X = (const float*)d_in[0];
    const float* E = (const float*)d_in[1];
    float* out = (float*)d_out;
    char* ws = (char*)d_ws;

    double*    loss   = (double*)(ws + WS_LOSS);
    int*       rcnt   = (int*)(ws + WS_RCNT);
    float*     e2     = (float*)(ws + WS_E2);
    float*     e2p    = (float*)(ws + WS_E2P);
    int*       counts = (int*)(ws + WS_COUNTS);
    int*       idx_ws = (int*)(ws + WS_IDX);
    int*       rlist  = (int*)(ws + WS_RLIST);
    float*     Et     = (float*)(ws + WS_ET);
    _Float16*  Pp     = (_Float16*)(ws + WS_P);

    k_prep<<<1024, 256, 0, stream>>>(E, e2, e2p, Et, Pp, counts, loss, rcnt);
    // A/B row split: control (r12-exact) vs nontemporal-X staging
    k_mainT<0><<<512, 256, 0, stream>>>(X, Pp, e2p, idx_ws, rlist, rcnt, 0);
    k_mainT<1><<<512, 256, 0, stream>>>(X, Pp, e2p, idx_ws, rlist, rcnt, 32768);
    k_refine<<<1024, 256, 0, stream>>>(X, Et, e2, rlist, rcnt, idx_ws);
    k_out<<<1024, 256, 0, stream>>>(X, E, idx_ws, out, counts, loss);
    k_fin<<<1, 256, 0, stream>>>(counts, loss, out);
}